// Round 4
// baseline (41.323 us; speedup 1.0000x reference)
//
#include <hip/hip_runtime.h>
#include <math.h>

#define HD 768
#define NL 3
#define BB 64
#define SS 512
#define NEG (-1e30f)
#define TOK_PER_WAVE 4
#define EMIS_BLOCKS 2048   // 2048*256 thr = 8192 waves * 4 tokens = 32768 tokens

__device__ __forceinline__ float lse3(float x, float y, float z) {
    float m = fmaxf(fmaxf(x, y), z);
    return m + __logf(__expf(x - m) + __expf(y - m) + __expf(z - m));
}

// Persistent-wave emissions GEMM: [B*S, 768] @ [768, 3] + b.
// Each wave preloads its lane's 36 W coefficients into registers ONCE
// (lane l owns float4 chunks l, l+64, l+128 of each row), then processes
// TOK_PER_WAVE tokens: 3 dwordx4 loads + 36 reg FMAs + 18 shfl + store each.
// Output layout: em[(b*S + s)*3 + j]  ([B,S,3]) for the CRF kernel.
__global__ __launch_bounds__(256) void emis_kernel(
    const float* __restrict__ hidden, const float* __restrict__ W,
    const float* __restrict__ bias, float* __restrict__ em,
    float* __restrict__ out) {
    if (blockIdx.x == 0 && threadIdx.x == 0) out[0] = 0.f;  // init for atomics
    int gid  = blockIdx.x * blockDim.x + threadIdx.x;
    int wave = gid >> 6;
    int lane = threadIdx.x & 63;

    // Preload W fragment: 12 k-chunks x 4 elems x 3 outputs = 36 regs.
    float Wr[3][4][3];
#pragma unroll
    for (int i = 0; i < 3; ++i) {
        int k = (lane + 64 * i) * 4;
#pragma unroll
        for (int e = 0; e < 4; ++e)
#pragma unroll
            for (int j = 0; j < 3; ++j)
                Wr[i][e][j] = W[(k + e) * 3 + j];
    }
    float b0 = bias[0], b1 = bias[1], b2 = bias[2];

#pragma unroll
    for (int t = 0; t < TOK_PER_WAVE; ++t) {
        int tok = wave * TOK_PER_WAVE + t;
        const float4* h4 = (const float4*)(hidden + (size_t)tok * HD);
        float a0 = 0.f, a1 = 0.f, a2 = 0.f;
#pragma unroll
        for (int i = 0; i < 3; ++i) {
            float4 v = h4[lane + 64 * i];
            a0 = fmaf(v.x, Wr[i][0][0], a0);
            a1 = fmaf(v.x, Wr[i][0][1], a1);
            a2 = fmaf(v.x, Wr[i][0][2], a2);
            a0 = fmaf(v.y, Wr[i][1][0], a0);
            a1 = fmaf(v.y, Wr[i][1][1], a1);
            a2 = fmaf(v.y, Wr[i][1][2], a2);
            a0 = fmaf(v.z, Wr[i][2][0], a0);
            a1 = fmaf(v.z, Wr[i][2][1], a1);
            a2 = fmaf(v.z, Wr[i][2][2], a2);
            a0 = fmaf(v.w, Wr[i][3][0], a0);
            a1 = fmaf(v.w, Wr[i][3][1], a1);
            a2 = fmaf(v.w, Wr[i][3][2], a2);
        }
#pragma unroll
        for (int off = 32; off; off >>= 1) {
            a0 += __shfl_down(a0, off);
            a1 += __shfl_down(a1, off);
            a2 += __shfl_down(a2, off);
        }
        if (lane == 0) {
            int b = tok >> 9;           // tok / SS
            int s = tok & (SS - 1);     // tok % SS
            float* o = em + ((size_t)b * SS + s) * NL;
            o[0] = a0 + b0;
            o[1] = a1 + b1;
            o[2] = a2 + b2;
        }
    }
}

// One wave per batch (blockIdx.x = b). Lane l owns steps [8l, 8l+8) (step 0 is
// the alpha0 init, excluded by predicate). All loads coalesced+hoisted:
// 6 float4 of emissions, 2 int4 labels, 2 int4 mask per lane. Each lane builds
// its chunk's 3x3 semiring matrix; shfl_down tree (increasing offsets —
// non-commutative) combines. Gold score / last-tag reduced alongside.
__global__ __launch_bounds__(64) void crf_scan_kernel(
    const float* __restrict__ em,          // [B,S,3]
    const int* __restrict__ mask,          // [B,S]
    const int* __restrict__ labels,        // [B,S]
    const float* __restrict__ startT, const float* __restrict__ endT,
    const float* __restrict__ trans, float* __restrict__ out) {
    int b = blockIdx.x;
    int l = threadIdx.x;

    float T[3][3];
#pragma unroll
    for (int i = 0; i < 3; ++i)
#pragma unroll
        for (int j = 0; j < 3; ++j) T[i][j] = trans[i * 3 + j];

    const float* emb = em + (size_t)b * SS * NL;
    const int*   tg  = labels + b * SS;
    const int*   mk  = mask + b * SS;
    int s0 = l * 8;

    // hoisted coalesced loads
    float4 E[6];
    const float4* ep = (const float4*)(emb + (size_t)s0 * NL);
#pragma unroll
    for (int i = 0; i < 6; ++i) E[i] = ep[i];
    float f[24];
#pragma unroll
    for (int i = 0; i < 6; ++i) {
        f[i * 4 + 0] = E[i].x; f[i * 4 + 1] = E[i].y;
        f[i * 4 + 2] = E[i].z; f[i * 4 + 3] = E[i].w;
    }
    int4 ta = ((const int4*)(tg + s0))[0];
    int4 tb = ((const int4*)(tg + s0))[1];
    int4 ma = ((const int4*)(mk + s0))[0];
    int4 mb = ((const int4*)(mk + s0))[1];
    int tgs[8] = {ta.x, ta.y, ta.z, ta.w, tb.x, tb.y, tb.z, tb.w};
    int mks[8] = {ma.x, ma.y, ma.z, ma.w, mb.x, mb.y, mb.z, mb.w};
    int prev = (l > 0) ? tg[s0 - 1] : 0;
    if (prev < 0) prev = 0;

    float P[3][3];
    bool first = true;
    float gold = 0.f;
    int last_s = -1, last_t = 0;

#pragma unroll
    for (int k = 0; k < 8; ++k) {
        int s = s0 + k;
        float e0 = f[k * 3 + 0], e1 = f[k * 3 + 1], e2 = f[k * 3 + 2];
        int t = tgs[k]; if (t < 0) t = 0;
        bool active = (s > 0) && (mks[k] != 0);
        if (active) {
            float ev = (t == 0 ? e0 : (t == 1 ? e1 : e2));
            gold += ev + T[prev][t];
            last_s = s; last_t = t;
            if (first) {
                first = false;
#pragma unroll
                for (int i = 0; i < 3; ++i) {
                    P[i][0] = T[i][0] + e0;
                    P[i][1] = T[i][1] + e1;
                    P[i][2] = T[i][2] + e2;
                }
            } else {
                float N[3][3];
#pragma unroll
                for (int i = 0; i < 3; ++i) {
                    float a0 = P[i][0], a1 = P[i][1], a2 = P[i][2];
                    N[i][0] = lse3(a0 + T[0][0], a1 + T[1][0], a2 + T[2][0]) + e0;
                    N[i][1] = lse3(a0 + T[0][1], a1 + T[1][1], a2 + T[2][1]) + e1;
                    N[i][2] = lse3(a0 + T[0][2], a1 + T[1][2], a2 + T[2][2]) + e2;
                }
#pragma unroll
                for (int i = 0; i < 3; ++i) {
                    P[i][0] = N[i][0]; P[i][1] = N[i][1]; P[i][2] = N[i][2];
                }
            }
        }
        prev = t;
    }
    if (first) {  // fully-masked chunk: identity
#pragma unroll
        for (int i = 0; i < 3; ++i)
#pragma unroll
            for (int j = 0; j < 3; ++j) P[i][j] = (i == j) ? 0.f : NEG;
    }

    // tree combine: offsets MUST increase for the non-commutative product.
#pragma unroll
    for (int off = 1; off < 64; off <<= 1) {
        float Bm[3][3];
#pragma unroll
        for (int i = 0; i < 3; ++i)
#pragma unroll
            for (int j = 0; j < 3; ++j) Bm[i][j] = __shfl_down(P[i][j], off);
        float N[3][3];
#pragma unroll
        for (int i = 0; i < 3; ++i) {
            float a0 = P[i][0], a1 = P[i][1], a2 = P[i][2];
#pragma unroll
            for (int j = 0; j < 3; ++j)
                N[i][j] = lse3(a0 + Bm[0][j], a1 + Bm[1][j], a2 + Bm[2][j]);
        }
#pragma unroll
        for (int i = 0; i < 3; ++i)
#pragma unroll
            for (int j = 0; j < 3; ++j) P[i][j] = N[i][j];

        gold += __shfl_down(gold, off);
        int os = __shfl_down(last_s, off);
        int ot = __shfl_down(last_t, off);
        if (os > last_s) { last_s = os; last_t = ot; }
    }

    if (l == 0) {
        int t0 = tgs[0]; if (t0 < 0) t0 = 0;
        float e00 = f[0], e01 = f[1], e02 = f[2];
        float a0 = startT[0] + e00, a1 = startT[1] + e01, a2 = startT[2] + e02;
        float f0 = lse3(a0 + P[0][0], a1 + P[1][0], a2 + P[2][0]);
        float f1 = lse3(a0 + P[0][1], a1 + P[1][1], a2 + P[2][1]);
        float f2 = lse3(a0 + P[0][2], a1 + P[1][2], a2 + P[2][2]);
        float logZ = lse3(f0 + endT[0], f1 + endT[1], f2 + endT[2]);
        float sc0 = startT[t0] + (t0 == 0 ? e00 : (t0 == 1 ? e01 : e02));
        if (last_s < 0) last_t = t0;     // no masked step beyond 0
        float score = sc0 + gold + endT[last_t];
        atomicAdd(out, (logZ - score) * (1.0f / BB));
    }
}

extern "C" void kernel_launch(void* const* d_in, const int* in_sizes, int n_in,
                              void* d_out, int out_size, void* d_ws, size_t ws_size,
                              hipStream_t stream) {
    const float* hidden = (const float*)d_in[0];
    const float* W      = (const float*)d_in[1];
    const float* bias   = (const float*)d_in[2];
    const float* startT = (const float*)d_in[3];
    const float* endT   = (const float*)d_in[4];
    const float* trans  = (const float*)d_in[5];
    const int*   mask   = (const int*)d_in[6];
    const int*   labels = (const int*)d_in[7];
    float* out = (float*)d_out;

    float* em = (float*)d_ws;                   // B*S*3 floats = 384 KiB

    emis_kernel<<<EMIS_BLOCKS, 256, 0, stream>>>(hidden, W, bias, em, out);
    crf_scan_kernel<<<BB, 64, 0, stream>>>(em, mask, labels, startT, endT,
                                           trans, out);
}

// Round 5
// 30.961 us; speedup vs baseline: 1.3347x; 1.3347x over previous
//
#include <hip/hip_runtime.h>
#include <math.h>

#define HD 768
#define NL 3
#define BB 64
#define SS 512
#define NEG (-1e30f)

__device__ __forceinline__ float lse3(float x, float y, float z) {
    float m = fmaxf(fmaxf(x, y), z);
    return m + __logf(__expf(x - m) + __expf(y - m) + __expf(z - m));
}

// One wave (64 lanes) per token. Lane l loads float4 chunks l, l+64, l+128 of
// the 768-float hidden row, accumulates 3 dot products, wave-reduces.
// Output layout: em[(b*S + s)*3 + j]  ([B,S,3]) so the CRF kernel's per-lane
// 8-step chunks are contiguous (coalesced float4 loads).
__global__ __launch_bounds__(256) void emis_kernel(
    const float* __restrict__ hidden, const float* __restrict__ W,
    const float* __restrict__ bias, float* __restrict__ em,
    float* __restrict__ out) {
    if (blockIdx.x == 0 && threadIdx.x == 0) out[0] = 0.f;  // init for atomics
    int gid  = blockIdx.x * blockDim.x + threadIdx.x;
    int wave = gid >> 6;
    int lane = threadIdx.x & 63;
    int BS = BB * SS;
    if (wave >= BS) return;
    const float4* h4 = (const float4*)(hidden + (size_t)wave * HD);
    float a0 = 0.f, a1 = 0.f, a2 = 0.f;
#pragma unroll
    for (int i = 0; i < 3; ++i) {
        int k4 = lane + 64 * i;          // float4 index within the row
        float4 v = h4[k4];
        int k = k4 * 4;
        a0 = fmaf(v.x, W[(k + 0) * 3 + 0], a0);
        a1 = fmaf(v.x, W[(k + 0) * 3 + 1], a1);
        a2 = fmaf(v.x, W[(k + 0) * 3 + 2], a2);
        a0 = fmaf(v.y, W[(k + 1) * 3 + 0], a0);
        a1 = fmaf(v.y, W[(k + 1) * 3 + 1], a1);
        a2 = fmaf(v.y, W[(k + 1) * 3 + 2], a2);
        a0 = fmaf(v.z, W[(k + 2) * 3 + 0], a0);
        a1 = fmaf(v.z, W[(k + 2) * 3 + 1], a1);
        a2 = fmaf(v.z, W[(k + 2) * 3 + 2], a2);
        a0 = fmaf(v.w, W[(k + 3) * 3 + 0], a0);
        a1 = fmaf(v.w, W[(k + 3) * 3 + 1], a1);
        a2 = fmaf(v.w, W[(k + 3) * 3 + 2], a2);
    }
#pragma unroll
    for (int off = 32; off; off >>= 1) {
        a0 += __shfl_down(a0, off);
        a1 += __shfl_down(a1, off);
        a2 += __shfl_down(a2, off);
    }
    if (lane == 0) {
        int b = wave >> 9;           // wave / SS
        int s = wave & (SS - 1);     // wave % SS
        float* o = em + ((size_t)b * SS + s) * NL;
        o[0] = a0 + bias[0];
        o[1] = a1 + bias[1];
        o[2] = a2 + bias[2];
    }
}

// One wave per batch. Lane l owns steps [8l, 8l+8). FULLY register-resident:
// no runtime-indexed arrays (T/P as named scalars, selects via cndmask),
// no data-dependent branches (active-select per step). Semiring product of
// each chunk, then 6-level shfl_down tree (increasing offsets, non-comm).
__global__ __launch_bounds__(64) void crf_scan_kernel(
    const float* __restrict__ em,          // [B,S,3]
    const int* __restrict__ mask,          // [B,S]
    const int* __restrict__ labels,        // [B,S]
    const float* __restrict__ startT, const float* __restrict__ endT,
    const float* __restrict__ trans, float* __restrict__ out) {
    int b = blockIdx.x;
    int l = threadIdx.x;

    float T00 = trans[0], T01 = trans[1], T02 = trans[2];
    float T10 = trans[3], T11 = trans[4], T12 = trans[5];
    float T20 = trans[6], T21 = trans[7], T22 = trans[8];

    const float* emb = em + (size_t)b * SS * NL;
    const int*   tg  = labels + b * SS;
    const int*   mk  = mask + b * SS;
    int s0 = l * 8;

    const float4* ep = (const float4*)(emb + (size_t)s0 * NL);
    float4 E0 = ep[0], E1 = ep[1], E2 = ep[2];
    float4 E3 = ep[3], E4 = ep[4], E5 = ep[5];
    int4 ta  = ((const int4*)(tg + s0))[0];
    int4 tb4 = ((const int4*)(tg + s0))[1];
    int4 ma  = ((const int4*)(mk + s0))[0];
    int4 mb4 = ((const int4*)(mk + s0))[1];
    int pv = (l > 0) ? tg[s0 - 1] : 0;
    int prev = pv < 0 ? 0 : pv;

    float P00, P01, P02, P10, P11, P12, P20, P21, P22;
    float gold = 0.f;
    int last_s = -1, last_t = 0;

#define GOLD(kk, ee0, ee1, ee2, tt, mm, ACT)                                   \
    int t = (tt) < 0 ? 0 : (tt);                                               \
    bool act = (ACT) && ((mm) != 0);                                           \
    {                                                                          \
        float ev = (t == 0) ? (ee0) : ((t == 1) ? (ee1) : (ee2));              \
        float r0 = (t == 0) ? T00 : ((t == 1) ? T01 : T02);                    \
        float r1 = (t == 0) ? T10 : ((t == 1) ? T11 : T12);                    \
        float r2 = (t == 0) ? T20 : ((t == 1) ? T21 : T22);                    \
        float tpt = (prev == 0) ? r0 : ((prev == 1) ? r1 : r2);                \
        gold += act ? (ev + tpt) : 0.f;                                        \
        last_t = act ? t : last_t;                                             \
        last_s = act ? (s0 + (kk)) : last_s;                                   \
        prev = t;                                                              \
    }

    // step 0 of the chunk: P = act ? M : Identity  (M[i][j] = T[i][j]+e_j)
#define STEP0(ee0, ee1, ee2, tt, mm) {                                         \
    GOLD(0, ee0, ee1, ee2, tt, mm, (s0 > 0))                                   \
    P00 = act ? (T00 + (ee0)) : 0.f;                                           \
    P01 = act ? (T01 + (ee1)) : NEG;                                           \
    P02 = act ? (T02 + (ee2)) : NEG;                                           \
    P10 = act ? (T10 + (ee0)) : NEG;                                           \
    P11 = act ? (T11 + (ee1)) : 0.f;                                           \
    P12 = act ? (T12 + (ee2)) : NEG;                                           \
    P20 = act ? (T20 + (ee0)) : NEG;                                           \
    P21 = act ? (T21 + (ee1)) : NEG;                                           \
    P22 = act ? (T22 + (ee2)) : 0.f;                                           \
}

    // steps 1..7: P = act ? P ⊗ M : P   (e_j factored out of the lse)
#define STEPK(kk, ee0, ee1, ee2, tt, mm) {                                     \
    GOLD(kk, ee0, ee1, ee2, tt, mm, true)                                      \
    float n00 = lse3(P00 + T00, P01 + T10, P02 + T20) + (ee0);                 \
    float n01 = lse3(P00 + T01, P01 + T11, P02 + T21) + (ee1);                 \
    float n02 = lse3(P00 + T02, P01 + T12, P02 + T22) + (ee2);                 \
    float n10 = lse3(P10 + T00, P11 + T10, P12 + T20) + (ee0);                 \
    float n11 = lse3(P10 + T01, P11 + T11, P12 + T21) + (ee1);                 \
    float n12 = lse3(P10 + T02, P11 + T12, P12 + T22) + (ee2);                 \
    float n20 = lse3(P20 + T00, P21 + T10, P22 + T20) + (ee0);                 \
    float n21 = lse3(P20 + T01, P21 + T11, P22 + T21) + (ee1);                 \
    float n22 = lse3(P20 + T02, P21 + T12, P22 + T22) + (ee2);                 \
    P00 = act ? n00 : P00; P01 = act ? n01 : P01; P02 = act ? n02 : P02;       \
    P10 = act ? n10 : P10; P11 = act ? n11 : P11; P12 = act ? n12 : P12;       \
    P20 = act ? n20 : P20; P21 = act ? n21 : P21; P22 = act ? n22 : P22;       \
}

    STEP0(    E0.x, E0.y, E0.z, ta.x,  ma.x)
    STEPK(1,  E0.w, E1.x, E1.y, ta.y,  ma.y)
    STEPK(2,  E1.z, E1.w, E2.x, ta.z,  ma.z)
    STEPK(3,  E2.y, E2.z, E2.w, ta.w,  ma.w)
    STEPK(4,  E3.x, E3.y, E3.z, tb4.x, mb4.x)
    STEPK(5,  E3.w, E4.x, E4.y, tb4.y, mb4.y)
    STEPK(6,  E4.z, E4.w, E5.x, tb4.z, mb4.z)
    STEPK(7,  E5.y, E5.z, E5.w, tb4.w, mb4.w)

    // tree combine: offsets MUST increase (non-commutative product).
#pragma unroll
    for (int off = 1; off < 64; off <<= 1) {
        float B00 = __shfl_down(P00, off), B01 = __shfl_down(P01, off);
        float B02 = __shfl_down(P02, off), B10 = __shfl_down(P10, off);
        float B11 = __shfl_down(P11, off), B12 = __shfl_down(P12, off);
        float B20 = __shfl_down(P20, off), B21 = __shfl_down(P21, off);
        float B22 = __shfl_down(P22, off);
        float n00 = lse3(P00 + B00, P01 + B10, P02 + B20);
        float n01 = lse3(P00 + B01, P01 + B11, P02 + B21);
        float n02 = lse3(P00 + B02, P01 + B12, P02 + B22);
        float n10 = lse3(P10 + B00, P11 + B10, P12 + B20);
        float n11 = lse3(P10 + B01, P11 + B11, P12 + B21);
        float n12 = lse3(P10 + B02, P11 + B12, P12 + B22);
        float n20 = lse3(P20 + B00, P21 + B10, P22 + B20);
        float n21 = lse3(P20 + B01, P21 + B11, P22 + B21);
        float n22 = lse3(P20 + B02, P21 + B12, P22 + B22);
        P00 = n00; P01 = n01; P02 = n02;
        P10 = n10; P11 = n11; P12 = n12;
        P20 = n20; P21 = n21; P22 = n22;

        gold += __shfl_down(gold, off);
        int os = __shfl_down(last_s, off);
        int ot = __shfl_down(last_t, off);
        if (os > last_s) { last_s = os; last_t = ot; }
    }

    if (l == 0) {
        int t0 = ta.x < 0 ? 0 : ta.x;
        float st0 = startT[0], st1 = startT[1], st2 = startT[2];
        float en0 = endT[0],   en1 = endT[1],   en2 = endT[2];
        float e00 = E0.x, e01 = E0.y, e02 = E0.z;
        float a0 = st0 + e00, a1 = st1 + e01, a2 = st2 + e02;
        float f0 = lse3(a0 + P00, a1 + P10, a2 + P20);
        float f1 = lse3(a0 + P01, a1 + P11, a2 + P21);
        float f2 = lse3(a0 + P02, a1 + P12, a2 + P22);
        float logZ = lse3(f0 + en0, f1 + en1, f2 + en2);
        float sc0 = ((t0 == 0) ? st0 : ((t0 == 1) ? st1 : st2)) +
                    ((t0 == 0) ? e00 : ((t0 == 1) ? e01 : e02));
        if (last_s < 0) last_t = t0;     // no active step beyond 0
        float endv = (last_t == 0) ? en0 : ((last_t == 1) ? en1 : en2);
        float score = sc0 + gold + endv;
        atomicAdd(out, (logZ - score) * (1.0f / BB));
    }
}

extern "C" void kernel_launch(void* const* d_in, const int* in_sizes, int n_in,
                              void* d_out, int out_size, void* d_ws, size_t ws_size,
                              hipStream_t stream) {
    const float* hidden = (const float*)d_in[0];
    const float* W      = (const float*)d_in[1];
    const float* bias   = (const float*)d_in[2];
    const float* startT = (const float*)d_in[3];
    const float* endT   = (const float*)d_in[4];
    const float* trans  = (const float*)d_in[5];
    const int*   mask   = (const int*)d_in[6];
    const int*   labels = (const int*)d_in[7];
    float* out = (float*)d_out;

    float* em = (float*)d_ws;                   // B*S*3 floats = 384 KiB

    int BS = BB * SS;                           // 32768 tokens, one wave each
    int blocks = BS / 4;                        // 4 waves per 256-thread block
    emis_kernel<<<blocks, 256, 0, stream>>>(hidden, W, bias, em, out);
    crf_scan_kernel<<<BB, 64, 0, stream>>>(em, mask, labels, startT, endT,
                                           trans, out);
}